// Round 4
// baseline (1231.144 us; speedup 1.0000x reference)
//
#include <hip/hip_runtime.h>
#include <hip/hip_bf16.h>

#define BATCH 4096

typedef unsigned short u16;

__device__ inline float bf2f(unsigned int v) {
    union { unsigned int i; float f; } u;
    u.i = v << 16;
    return u.f;
}
__device__ inline u16 f2bf(float f) {
    union { float f; unsigned int i; } u;
    u.f = f;
    unsigned int lsb = (u.i >> 16) & 1u;
    unsigned int r = u.i + 0x7fffu + lsb;   // RNE
    if ((u.i & 0x7f800000u) == 0x7f800000u) r = u.i;  // inf/nan passthrough
    return (u16)(r >> 16);
}

// ---------------------------------------------------------------------------
// Fused: gabor-bank build + conv1(1->32,3x3,pad1) + relu + pool2
//        + conv2(32->64,3x3,pad1) + bias + relu + pool2
// One block per image. a1 kept in LDS. Output a2: (4096, 64, 7, 7) bf16.
// ---------------------------------------------------------------------------
__global__ __launch_bounds__(256) void fused_conv_kernel(
        const float* __restrict__ x,
        const float* __restrict__ theta, const float* __restrict__ sigma,
        const float* __restrict__ gamma, const float* __restrict__ lambd,
        const float* __restrict__ psi,
        const float* __restrict__ conv2_w, const float* __restrict__ conv2_b,
        u16* __restrict__ a2) {
    __shared__ float img[30][31];        // padded 28x28 (rows/cols 1..28)
    __shared__ float w1s[32][9];
    __shared__ float a1s[32][16][16];    // padded 14x14 (rows/cols 1..14)
    __shared__ float w2s[16][32][9];     // one oc-group of conv2 weights

    int n = blockIdx.x;
    int tid = threadIdx.x;

    for (int i = tid; i < 30 * 31; i += 256) (&img[0][0])[i] = 0.0f;
    for (int i = tid; i < 32 * 16 * 16; i += 256) (&a1s[0][0][0])[i] = 0.0f;
    // NOTE: strided loop, NOT `if (tid < 288)` — block is 256 threads; the
    // round-2 version left taps 256..287 (channels 28..31) uninitialized.
    for (int idx = tid; idx < 32 * 9; idx += 256) {
        int g = idx / 9, t = idx % 9;
        int i = t / 3, j = t % 3;        // (H, W) tap
        float xg = (float)i - 1.0f;      // meshgrid 'ij': xg = offs[row]
        float yg = (float)j - 1.0f;
        float v;
        if (g < 16) {
            float th = theta[g];
            float c = cosf(th), s = sinf(th);
            float xt = xg * c + yg * s;
            float yt = -xg * s + yg * c;
            float sx = sigma[g];
            float sy = sx / gamma[g];
            float env =
                expf(-0.5f * (xt * xt / (sx * sx) + yt * yt / (sy * sy)));
            float car =
                cosf(6.28318530717958647692f * xt / lambd[g] + psi[g]);
            v = env * car;
        } else {
            v = (i == 1 && j == 1) ? 1.0f : 0.0f;
        }
        w1s[g][t] = v;
    }
    __syncthreads();

    const float* xim = x + (size_t)n * 784;
    for (int i = tid; i < 784; i += 256) {
        int r = i / 28, c = i % 28;
        img[r + 1][c + 1] = xim[i];
    }
    __syncthreads();

    // ---- conv1 + relu + pool -> a1s (padded) ----
    for (int idx = tid; idx < 32 * 196; idx += 256) {
        int ch = idx / 196;
        int p = idx % 196;
        int oy = p / 14, ox = p % 14;
        int iy = 2 * oy, ix = 2 * ox;
        float patch[4][4];
#pragma unroll
        for (int r = 0; r < 4; ++r)
#pragma unroll
            for (int c = 0; c < 4; ++c) patch[r][c] = img[iy + r][ix + c];
        const float* wc = &w1s[ch][0];
        float w0 = wc[0], w1 = wc[1], w2 = wc[2], w3 = wc[3], w4 = wc[4],
              w5 = wc[5], w6 = wc[6], w7 = wc[7], w8 = wc[8];
        float best = -1e30f;
#pragma unroll
        for (int py = 0; py < 2; ++py)
#pragma unroll
            for (int px = 0; px < 2; ++px) {
                float acc = patch[py][px] * w0 + patch[py][px + 1] * w1 +
                            patch[py][px + 2] * w2 + patch[py + 1][px] * w3 +
                            patch[py + 1][px + 1] * w4 +
                            patch[py + 1][px + 2] * w5 +
                            patch[py + 2][px] * w6 +
                            patch[py + 2][px + 1] * w7 +
                            patch[py + 2][px + 2] * w8;
                best = fmaxf(best, acc);
            }
        a1s[ch][1 + oy][1 + ox] = fmaxf(best, 0.0f);
    }

    // ---- conv2 + bias + relu + pool, 16 ocs per group ----
    u16* dstn = a2 + (size_t)n * 3136;
    for (int g = 0; g < 4; ++g) {
        __syncthreads();
        const float* wsrc = conv2_w + (size_t)g * 16 * 288;
        for (int i = tid; i < 16 * 288; i += 256) (&w2s[0][0][0])[i] = wsrc[i];
        __syncthreads();

        if (tid < 196) {
            int pos = tid % 49;
            int oc4 = tid / 49;
            int oy = pos / 7, ox = pos % 7;
            int iy = 2 * oy, ix = 2 * ox;
            float acc[4][2][2];
#pragma unroll
            for (int j = 0; j < 4; ++j)
#pragma unroll
                for (int py = 0; py < 2; ++py)
#pragma unroll
                    for (int px = 0; px < 2; ++px) acc[j][py][px] = 0.0f;

            for (int ic = 0; ic < 32; ++ic) {
                float patch[4][4];
#pragma unroll
                for (int r = 0; r < 4; ++r)
#pragma unroll
                    for (int c = 0; c < 4; ++c)
                        patch[r][c] = a1s[ic][iy + r][ix + c];
#pragma unroll
                for (int j = 0; j < 4; ++j) {
                    const float* wp = &w2s[oc4 * 4 + j][ic][0];
                    float w0 = wp[0], w1 = wp[1], w2 = wp[2], w3 = wp[3],
                          w4 = wp[4], w5 = wp[5], w6 = wp[6], w7 = wp[7],
                          w8 = wp[8];
#pragma unroll
                    for (int py = 0; py < 2; ++py)
#pragma unroll
                        for (int px = 0; px < 2; ++px) {
                            acc[j][py][px] += patch[py][px] * w0 +
                                              patch[py][px + 1] * w1 +
                                              patch[py][px + 2] * w2 +
                                              patch[py + 1][px] * w3 +
                                              patch[py + 1][px + 1] * w4 +
                                              patch[py + 1][px + 2] * w5 +
                                              patch[py + 2][px] * w6 +
                                              patch[py + 2][px + 1] * w7 +
                                              patch[py + 2][px + 2] * w8;
                        }
                }
            }
#pragma unroll
            for (int j = 0; j < 4; ++j) {
                int ocl = oc4 * 4 + j;
                float b = conv2_b[g * 16 + ocl];
                float best = fmaxf(fmaxf(acc[j][0][0], acc[j][0][1]),
                                   fmaxf(acc[j][1][0], acc[j][1][1]));
                float v = fmaxf(best + b, 0.0f);
                dstn[(g * 16 + ocl) * 49 + pos] = f2bf(v);
            }
        }
    }
}

// ------------------------------------------------ fc1: (4096,3136)x(128,3136)^T
#define FC1_BM 32
#define FC1_BN 64
#define FC1_BK 32
__global__ __launch_bounds__(256) void fc1_kernel(
        const u16* __restrict__ A,   // bf16 activations (4096,3136)
        const float* __restrict__ W, const float* __restrict__ bias,
        float* __restrict__ H) {
    __shared__ float As[FC1_BK][FC1_BM + 4];  // As[k][m]
    __shared__ float Bs[FC1_BK][FC1_BN + 4];  // Bs[k][n]
    int bm = blockIdx.x;
    int bn = blockIdx.y;
    int tid = threadIdx.x;
    int tx = tid % 16;
    int ty = tid / 16;
    int m0 = bm * FC1_BM;
    int n0 = bn * FC1_BN;

    int am = tid / 8;            // 0..31
    int ak = (tid % 8) * 4;      // 0..28
    int wn = tid / 4;            // 0..63
    int wk = (tid % 4) * 4;      // 0,4,8,12 (+16 second chunk)

    float acc[2][4] = {{0.f, 0.f, 0.f, 0.f}, {0.f, 0.f, 0.f, 0.f}};

    for (int k0 = 0; k0 < 3136; k0 += FC1_BK) {
        uint2 ua = *(const uint2*)(A + (size_t)(m0 + am) * 3136 + k0 + ak);
        As[ak + 0][am] = bf2f(ua.x & 0xffffu);
        As[ak + 1][am] = bf2f(ua.x >> 16);
        As[ak + 2][am] = bf2f(ua.y & 0xffffu);
        As[ak + 3][am] = bf2f(ua.y >> 16);
        float4 vb0 = *(const float4*)(W + (size_t)(n0 + wn) * 3136 + k0 + wk);
        float4 vb1 =
            *(const float4*)(W + (size_t)(n0 + wn) * 3136 + k0 + wk + 16);
        Bs[wk + 0][wn] = vb0.x;
        Bs[wk + 1][wn] = vb0.y;
        Bs[wk + 2][wn] = vb0.z;
        Bs[wk + 3][wn] = vb0.w;
        Bs[wk + 16][wn] = vb1.x;
        Bs[wk + 17][wn] = vb1.y;
        Bs[wk + 18][wn] = vb1.z;
        Bs[wk + 19][wn] = vb1.w;
        __syncthreads();
#pragma unroll
        for (int kk = 0; kk < FC1_BK; ++kk) {
            float a0 = As[kk][ty * 2 + 0];
            float a1 = As[kk][ty * 2 + 1];
            float b0 = Bs[kk][tx * 4 + 0];
            float b1 = Bs[kk][tx * 4 + 1];
            float b2 = Bs[kk][tx * 4 + 2];
            float b3 = Bs[kk][tx * 4 + 3];
            acc[0][0] += a0 * b0; acc[0][1] += a0 * b1;
            acc[0][2] += a0 * b2; acc[0][3] += a0 * b3;
            acc[1][0] += a1 * b0; acc[1][1] += a1 * b1;
            acc[1][2] += a1 * b2; acc[1][3] += a1 * b3;
        }
        __syncthreads();
    }
#pragma unroll
    for (int i = 0; i < 2; ++i) {
#pragma unroll
        for (int j = 0; j < 4; ++j) {
            int nn = n0 + tx * 4 + j;
            float v = fmaxf(acc[i][j] + bias[nn], 0.0f);
            H[(size_t)(m0 + ty * 2 + i) * 128 + nn] = v;
        }
    }
}

// --------------------------------------------------------- fc2: (4096,128)->10
__global__ __launch_bounds__(256) void fc2_kernel(
        const float* __restrict__ H, const float* __restrict__ W,
        const float* __restrict__ bias, float* __restrict__ out) {
    int idx = blockIdx.x * 256 + threadIdx.x;
    if (idx >= BATCH * 10) return;
    int m = idx / 10, j = idx % 10;
    const float* hr = H + (size_t)m * 128;
    const float* wr = W + (size_t)j * 128;
    float acc = bias[j];
#pragma unroll 16
    for (int k = 0; k < 128; ++k) acc += hr[k] * wr[k];
    out[idx] = acc;
}

extern "C" void kernel_launch(void* const* d_in, const int* in_sizes, int n_in,
                              void* d_out, int out_size, void* d_ws,
                              size_t ws_size, hipStream_t stream) {
    const float* x       = (const float*)d_in[0];
    const float* theta   = (const float*)d_in[1];
    const float* sigma   = (const float*)d_in[2];
    const float* gamma   = (const float*)d_in[3];
    const float* lambd   = (const float*)d_in[4];
    const float* psi     = (const float*)d_in[5];
    const float* conv2_w = (const float*)d_in[6];
    const float* conv2_b = (const float*)d_in[7];
    const float* fc1_w   = (const float*)d_in[8];
    const float* fc1_b   = (const float*)d_in[9];
    const float* fc2_w   = (const float*)d_in[10];
    const float* fc2_b   = (const float*)d_in[11];
    float* out = (float*)d_out;

    // workspace: a2 bf16 (4096*3136*2 = 25,690,112 B) + h fp32 (2,097,152 B)
    char* ws = (char*)d_ws;
    u16* a2 = (u16*)ws;
    float* h = (float*)(ws + 25690112ull);

    fused_conv_kernel<<<BATCH, 256, 0, stream>>>(x, theta, sigma, gamma, lambd,
                                                 psi, conv2_w, conv2_b, a2);
    fc1_kernel<<<dim3(BATCH / FC1_BM, 128 / FC1_BN), 256, 0, stream>>>(
        a2, fc1_w, fc1_b, h);
    fc2_kernel<<<(BATCH * 10 + 255) / 256, 256, 0, stream>>>(h, fc2_w, fc2_b,
                                                             out);
}

// Round 5
// 396.936 us; speedup vs baseline: 3.1016x; 3.1016x over previous
//
#include <hip/hip_runtime.h>
#include <hip/hip_bf16.h>

#define BATCH 4096

typedef unsigned short u16;
typedef _Float16 half8 __attribute__((ext_vector_type(8)));
typedef float floatx4 __attribute__((ext_vector_type(4)));

__device__ inline float bf2f(unsigned int v) {
    union { unsigned int i; float f; } u;
    u.i = v << 16;
    return u.f;
}
__device__ inline u16 f2bf(float f) {
    union { float f; unsigned int i; } u;
    u.f = f;
    unsigned int lsb = (u.i >> 16) & 1u;
    unsigned int r = u.i + 0x7fffu + lsb;   // RNE
    if ((u.i & 0x7f800000u) == 0x7f800000u) r = u.i;
    return (u16)(r >> 16);
}

// ---------------------------------------------------------------------------
// Fused: gabor bank + conv1(1->32)+relu+pool (fp32 VALU, small)
//        + conv2(32->64) via 9 tap-wise MFMA GEMMs (fp16 in, fp32 acc)
//        + bias + relu + pool -> a2 (4096,64,7,7) bf16
// One block (256 thr = 4 waves) per image; 3 blocks/CU (51.5 KB LDS).
// conv2 as GEMM: M=196 pos (13 tiles of 16), N=64 oc (2 passes x 2 wave-tiles),
// K=32 ic per tap. A = a1 channel-last LDS, B = w2s[tap][oc][ic] (N,K format).
// ---------------------------------------------------------------------------
__global__ __launch_bounds__(256) void fused_conv_kernel(
        const float* __restrict__ x,
        const float* __restrict__ theta, const float* __restrict__ sigma,
        const float* __restrict__ gamma, const float* __restrict__ lambd,
        const float* __restrict__ psi,
        const float* __restrict__ conv2_w, const float* __restrict__ conv2_b,
        u16* __restrict__ a2) {
    // img/w1s (early, conv1) unioned with conv2 pre-pool buffer (late)
    __shared__ union {
        struct { float img[30][31]; float w1s[32][9]; } e;
        _Float16 out[32 * 196];           // one pass's 32 oc x 14x14
    } u;
    // a1 padded 14x14 -> [16][16], channel-last; ic stride 40 (not 32):
    // 80 B row stride => A-frag ds_read_b128 lands 2 lanes/bank (free),
    // vs 8-way conflict at 64 B stride; still 16 B aligned.
    __shared__ _Float16 a1s[16][16][40];
    __shared__ _Float16 w2s[9][32][32];   // [tap][oc-in-pass][ic]

    int n = blockIdx.x;
    int tid = threadIdx.x;

    for (int i = tid; i < 30 * 31; i += 256) (&u.e.img[0][0])[i] = 0.0f;
    for (int i = tid; i < 16 * 16 * 40; i += 256)
        (&a1s[0][0][0])[i] = (_Float16)0.0f;
    for (int idx = tid; idx < 32 * 9; idx += 256) {   // strided! (r2 bug)
        int g = idx / 9, t = idx % 9;
        int i = t / 3, j = t % 3;
        float xg = (float)i - 1.0f;      // meshgrid 'ij'
        float yg = (float)j - 1.0f;
        float v;
        if (g < 16) {
            float th = theta[g];
            float c = cosf(th), s = sinf(th);
            float xt = xg * c + yg * s;
            float yt = -xg * s + yg * c;
            float sx = sigma[g];
            float sy = sx / gamma[g];
            float env =
                expf(-0.5f * (xt * xt / (sx * sx) + yt * yt / (sy * sy)));
            float car =
                cosf(6.28318530717958647692f * xt / lambd[g] + psi[g]);
            v = env * car;
        } else {
            v = (i == 1 && j == 1) ? 1.0f : 0.0f;
        }
        u.e.w1s[g][t] = v;
    }
    __syncthreads();

    const float* xim = x + (size_t)n * 784;
    for (int i = tid; i < 784; i += 256)
        u.e.img[i / 28 + 1][i % 28 + 1] = xim[i];
    __syncthreads();

    // ---- conv1 + relu + pool -> a1s (f16, channel-last, padded) ----
    for (int idx = tid; idx < 32 * 196; idx += 256) {
        int ch = idx / 196;
        int p = idx % 196;
        int oy = p / 14, ox = p % 14;
        int iy = 2 * oy, ix = 2 * ox;
        float patch[4][4];
#pragma unroll
        for (int r = 0; r < 4; ++r)
#pragma unroll
            for (int c = 0; c < 4; ++c) patch[r][c] = u.e.img[iy + r][ix + c];
        const float* wc = &u.e.w1s[ch][0];
        float w0 = wc[0], w1 = wc[1], w2 = wc[2], w3 = wc[3], w4 = wc[4],
              w5 = wc[5], w6 = wc[6], w7 = wc[7], w8 = wc[8];
        float best = -1e30f;
#pragma unroll
        for (int py = 0; py < 2; ++py)
#pragma unroll
            for (int px = 0; px < 2; ++px) {
                float acc = patch[py][px] * w0 + patch[py][px + 1] * w1 +
                            patch[py][px + 2] * w2 + patch[py + 1][px] * w3 +
                            patch[py + 1][px + 1] * w4 +
                            patch[py + 1][px + 2] * w5 +
                            patch[py + 2][px] * w6 +
                            patch[py + 2][px + 1] * w7 +
                            patch[py + 2][px + 2] * w8;
                best = fmaxf(best, acc);
            }
        a1s[1 + oy][1 + ox][ch] = (_Float16)fmaxf(best, 0.0f);
    }
    __syncthreads();   // a1s ready; img dead (union region reused as u.out)

    int lane = tid & 63;
    int w = tid >> 6;                 // wave 0..3
    int l16 = lane & 15;
    int quad = lane >> 4;
    int nloc = (w & 1) * 16;          // wave's oc-tile within the pass
    int mtA = (w & 2) ? 7 : 0;        // wave's m-tile range (13 tiles total)
    int mtB = (w & 2) ? 13 : 7;
    u16* dstn = a2 + (size_t)n * 3136;

    for (int p = 0; p < 2; ++p) {     // 2 passes x 32 ocs
        const float* wp = conv2_w + (size_t)p * 32 * 288;
        for (int i = tid; i < 32 * 288; i += 256) {
            int oc = i / 288, r = i % 288, ic = r / 9, t = r % 9;
            w2s[t][oc][ic] = (_Float16)wp[i];
        }
        __syncthreads();

        // B fragments: lane holds W[oc = nloc+l16][ic = quad*8 .. +8]
        half8 bfrag[9];
#pragma unroll
        for (int t = 0; t < 9; ++t)
            bfrag[t] = *(const half8*)&w2s[t][nloc + l16][quad * 8];

        for (int mt = mtA; mt < mtB; ++mt) {
            int m = mt * 16 + l16;
            int pos = m < 196 ? m : 195;   // pad rows compute garbage, unstored
            int oy = pos / 14, ox = pos % 14;
            floatx4 acc0 = {0.f, 0.f, 0.f, 0.f};
            floatx4 acc1 = {0.f, 0.f, 0.f, 0.f};
#pragma unroll
            for (int t = 0; t < 9; ++t) {
                int dy = t / 3, dx = t % 3;
                half8 av =
                    *(const half8*)&a1s[oy + dy][ox + dx][quad * 8];
                if (t & 1)
                    acc1 = __builtin_amdgcn_mfma_f32_16x16x32_f16(
                        av, bfrag[t], acc1, 0, 0, 0);
                else
                    acc0 = __builtin_amdgcn_mfma_f32_16x16x32_f16(
                        av, bfrag[t], acc0, 0, 0, 0);
            }
            // C/D: col(l16)=oc, row(quad*4+r)=pos  [verified m89/m91 layout]
#pragma unroll
            for (int r = 0; r < 4; ++r) {
                int pm = mt * 16 + quad * 4 + r;
                if (pm < 196)
                    u.out[(nloc + l16) * 196 + pm] =
                        (_Float16)(acc0[r] + acc1[r]);
            }
        }
        __syncthreads();

        // pool 2x2 + bias + relu -> a2 bf16
        for (int i = tid; i < 32 * 49; i += 256) {
            int ocl = i / 49, pp = i % 49;
            int py = pp / 7, px = pp % 7;
            int base = ocl * 196 + py * 28 + px * 2;   // (2py)*14 + 2px
            float v0 = (float)u.out[base];
            float v1 = (float)u.out[base + 1];
            float v2 = (float)u.out[base + 14];
            float v3 = (float)u.out[base + 15];
            float mx = fmaxf(fmaxf(v0, v1), fmaxf(v2, v3));
            int oc = p * 32 + ocl;
            dstn[oc * 49 + pp] = f2bf(fmaxf(mx + conv2_b[oc], 0.0f));
        }
        __syncthreads();   // before next pass overwrites w2s / u.out
    }
}

// ------------------------------------------------ fc1: (4096,3136)x(128,3136)^T
#define FC1_BM 32
#define FC1_BN 64
#define FC1_BK 32
__global__ __launch_bounds__(256) void fc1_kernel(
        const u16* __restrict__ A,   // bf16 activations (4096,3136)
        const float* __restrict__ W, const float* __restrict__ bias,
        float* __restrict__ H) {
    __shared__ float As[FC1_BK][FC1_BM + 4];
    __shared__ float Bs[FC1_BK][FC1_BN + 4];
    int bm = blockIdx.x;
    int bn = blockIdx.y;
    int tid = threadIdx.x;
    int tx = tid % 16;
    int ty = tid / 16;
    int m0 = bm * FC1_BM;
    int n0 = bn * FC1_BN;

    int am = tid / 8;
    int ak = (tid % 8) * 4;
    int wn = tid / 4;
    int wk = (tid % 4) * 4;

    float acc[2][4] = {{0.f, 0.f, 0.f, 0.f}, {0.f, 0.f, 0.f, 0.f}};

    for (int k0 = 0; k0 < 3136; k0 += FC1_BK) {
        uint2 ua = *(const uint2*)(A + (size_t)(m0 + am) * 3136 + k0 + ak);
        As[ak + 0][am] = bf2f(ua.x & 0xffffu);
        As[ak + 1][am] = bf2f(ua.x >> 16);
        As[ak + 2][am] = bf2f(ua.y & 0xffffu);
        As[ak + 3][am] = bf2f(ua.y >> 16);
        float4 vb0 = *(const float4*)(W + (size_t)(n0 + wn) * 3136 + k0 + wk);
        float4 vb1 =
            *(const float4*)(W + (size_t)(n0 + wn) * 3136 + k0 + wk + 16);
        Bs[wk + 0][wn] = vb0.x;
        Bs[wk + 1][wn] = vb0.y;
        Bs[wk + 2][wn] = vb0.z;
        Bs[wk + 3][wn] = vb0.w;
        Bs[wk + 16][wn] = vb1.x;
        Bs[wk + 17][wn] = vb1.y;
        Bs[wk + 18][wn] = vb1.z;
        Bs[wk + 19][wn] = vb1.w;
        __syncthreads();
#pragma unroll
        for (int kk = 0; kk < FC1_BK; ++kk) {
            float a0 = As[kk][ty * 2 + 0];
            float a1 = As[kk][ty * 2 + 1];
            float b0 = Bs[kk][tx * 4 + 0];
            float b1 = Bs[kk][tx * 4 + 1];
            float b2 = Bs[kk][tx * 4 + 2];
            float b3 = Bs[kk][tx * 4 + 3];
            acc[0][0] += a0 * b0; acc[0][1] += a0 * b1;
            acc[0][2] += a0 * b2; acc[0][3] += a0 * b3;
            acc[1][0] += a1 * b0; acc[1][1] += a1 * b1;
            acc[1][2] += a1 * b2; acc[1][3] += a1 * b3;
        }
        __syncthreads();
    }
#pragma unroll
    for (int i = 0; i < 2; ++i) {
#pragma unroll
        for (int j = 0; j < 4; ++j) {
            int nn = n0 + tx * 4 + j;
            float v = fmaxf(acc[i][j] + bias[nn], 0.0f);
            H[(size_t)(m0 + ty * 2 + i) * 128 + nn] = v;
        }
    }
}

// --------------------------------------------------------- fc2: (4096,128)->10
__global__ __launch_bounds__(256) void fc2_kernel(
        const float* __restrict__ H, const float* __restrict__ W,
        const float* __restrict__ bias, float* __restrict__ out) {
    int idx = blockIdx.x * 256 + threadIdx.x;
    if (idx >= BATCH * 10) return;
    int m = idx / 10, j = idx % 10;
    const float* hr = H + (size_t)m * 128;
    const float* wr = W + (size_t)j * 128;
    float acc = bias[j];
#pragma unroll 16
    for (int k = 0; k < 128; ++k) acc += hr[k] * wr[k];
    out[idx] = acc;
}

extern "C" void kernel_launch(void* const* d_in, const int* in_sizes, int n_in,
                              void* d_out, int out_size, void* d_ws,
                              size_t ws_size, hipStream_t stream) {
    const float* x       = (const float*)d_in[0];
    const float* theta   = (const float*)d_in[1];
    const float* sigma   = (const float*)d_in[2];
    const float* gamma   = (const float*)d_in[3];
    const float* lambd   = (const float*)d_in[4];
    const float* psi     = (const float*)d_in[5];
    const float* conv2_w = (const float*)d_in[6];
    const float* conv2_b = (const float*)d_in[7];
    const float* fc1_w   = (const float*)d_in[8];
    const float* fc1_b   = (const float*)d_in[9];
    const float* fc2_w   = (const float*)d_in[10];
    const float* fc2_b   = (const float*)d_in[11];
    float* out = (float*)d_out;

    // workspace: a2 bf16 (4096*3136*2 = 25,690,112 B) + h fp32 (2,097,152 B)
    char* ws = (char*)d_ws;
    u16* a2 = (u16*)ws;
    float* h = (float*)(ws + 25690112ull);

    fused_conv_kernel<<<BATCH, 256, 0, stream>>>(x, theta, sigma, gamma, lambd,
                                                 psi, conv2_w, conv2_b, a2);
    fc1_kernel<<<dim3(BATCH / FC1_BM, 128 / FC1_BN), 256, 0, stream>>>(
        a2, fc1_w, fc1_b, h);
    fc2_kernel<<<(BATCH * 10 + 255) / 256, 256, 0, stream>>>(h, fc2_w, fc2_b,
                                                             out);
}

// Round 6
// 249.806 us; speedup vs baseline: 4.9284x; 1.5890x over previous
//
#include <hip/hip_runtime.h>
#include <hip/hip_bf16.h>

#define BATCH 4096

typedef unsigned short u16;
typedef _Float16 half8 __attribute__((ext_vector_type(8)));
typedef short bs8 __attribute__((ext_vector_type(8)));     // bf16x8 frag
typedef float floatx4 __attribute__((ext_vector_type(4)));

__device__ inline float bf2f(unsigned int v) {
    union { unsigned int i; float f; } u;
    u.i = v << 16;
    return u.f;
}
__device__ inline u16 f2bf(float f) {
    union { float f; unsigned int i; } u;
    u.f = f;
    unsigned int lsb = (u.i >> 16) & 1u;
    unsigned int r = u.i + 0x7fffu + lsb;   // RNE
    if ((u.i & 0x7f800000u) == 0x7f800000u) r = u.i;
    return (u16)(r >> 16);
}

// ---------------------------------------------------------------------------
// Prep (runs once, all weights L2-resident afterwards):
//  R1: gabor+identity bank -> w1g fp32[32*9]
//  R2: conv2_w (64,32,3,3) fp32 -> w2h f16 [tap][oc][ic]
//  R3: fc1_w (128,3136) fp32 -> wbf bf16 [n][k'], k' = pool*64+oc permuted
//      (matches pos-major a2 so both fc1 operands stream contiguously)
// ---------------------------------------------------------------------------
__global__ __launch_bounds__(256) void prep_kernel(
        const float* __restrict__ theta, const float* __restrict__ sigma,
        const float* __restrict__ gamma, const float* __restrict__ lambd,
        const float* __restrict__ psi, const float* __restrict__ conv2_w,
        const float* __restrict__ fc1_w, float* __restrict__ w1g,
        _Float16* __restrict__ w2h, u16* __restrict__ wbf) {
    int id = blockIdx.x * 256 + threadIdx.x;
    if (id < 288) {
        int g = id / 9, t = id % 9;
        int i = t / 3, j = t % 3;
        float xg = (float)i - 1.0f;      // meshgrid 'ij'
        float yg = (float)j - 1.0f;
        float v;
        if (g < 16) {
            float th = theta[g];
            float c = cosf(th), s = sinf(th);
            float xt = xg * c + yg * s;
            float yt = -xg * s + yg * c;
            float sx = sigma[g];
            float sy = sx / gamma[g];
            float env =
                expf(-0.5f * (xt * xt / (sx * sx) + yt * yt / (sy * sy)));
            float car =
                cosf(6.28318530717958647692f * xt / lambd[g] + psi[g]);
            v = env * car;
        } else {
            v = (i == 1 && j == 1) ? 1.0f : 0.0f;
        }
        w1g[id] = v;
    } else if (id < 288 + 18432) {
        int t2 = id - 288;
        int tap = t2 / 2048, rem = t2 % 2048;
        int oc = rem / 32, ic = rem % 32;
        w2h[t2] = (_Float16)conv2_w[(oc * 32 + ic) * 9 + tap];
    } else if (id < 288 + 18432 + 401408) {
        int t3 = id - 288 - 18432;
        int nrow = t3 / 3136, kp = t3 % 3136;
        int pool = kp / 64, oc = kp % 64;
        wbf[t3] = f2bf(fc1_w[(size_t)nrow * 3136 + oc * 49 + pool]);
    }
}

// ---------------------------------------------------------------------------
// Fused conv: conv1(1->32)+relu+pool (fp32 VALU) -> a1s f16 LDS
//             conv2(32->64) 9 tap-wise MFMA GEMMs, M pool-major so the 2x2
//             pool window lives in one lane's 4 C-regs -> reg max+bias+relu
//             -> a2 pos-major (4096)[49][64] bf16.  No w2 LDS, no out LDS.
// ---------------------------------------------------------------------------
__global__ __launch_bounds__(256) void fused_conv_kernel(
        const float* __restrict__ x, const float* __restrict__ w1g,
        const _Float16* __restrict__ w2h, const float* __restrict__ conv2_b,
        u16* __restrict__ a2) {
    __shared__ float img[30][31];
    __shared__ float w1s[32][9];
    __shared__ _Float16 a1s[16][16][40];  // ic stride 40: 2-way-free b128 reads

    int n = blockIdx.x;
    int tid = threadIdx.x;

    for (int i = tid; i < 30 * 31; i += 256) (&img[0][0])[i] = 0.0f;
    for (int i = tid; i < 16 * 16 * 40; i += 256)
        (&a1s[0][0][0])[i] = (_Float16)0.0f;
    for (int i = tid; i < 288; i += 256) (&w1s[0][0])[i] = w1g[i];
    __syncthreads();

    const float* xim = x + (size_t)n * 784;
    for (int i = tid; i < 784; i += 256)
        img[i / 28 + 1][i % 28 + 1] = xim[i];
    __syncthreads();

    // ---- conv1 + relu + pool -> a1s (f16, channel-last, padded) ----
    for (int idx = tid; idx < 32 * 196; idx += 256) {
        int ch = idx / 196;
        int p = idx % 196;
        int oy = p / 14, ox = p % 14;
        int iy = 2 * oy, ix = 2 * ox;
        float patch[4][4];
#pragma unroll
        for (int r = 0; r < 4; ++r)
#pragma unroll
            for (int c = 0; c < 4; ++c) patch[r][c] = img[iy + r][ix + c];
        const float* wc = &w1s[ch][0];
        float w0 = wc[0], w1 = wc[1], w2 = wc[2], w3 = wc[3], w4 = wc[4],
              w5 = wc[5], w6 = wc[6], w7 = wc[7], w8 = wc[8];
        float best = -1e30f;
#pragma unroll
        for (int py = 0; py < 2; ++py)
#pragma unroll
            for (int px = 0; px < 2; ++px) {
                float acc = patch[py][px] * w0 + patch[py][px + 1] * w1 +
                            patch[py][px + 2] * w2 + patch[py + 1][px] * w3 +
                            patch[py + 1][px + 1] * w4 +
                            patch[py + 1][px + 2] * w5 +
                            patch[py + 2][px] * w6 +
                            patch[py + 2][px + 1] * w7 +
                            patch[py + 2][px + 2] * w8;
                best = fmaxf(best, acc);
            }
        a1s[1 + oy][1 + ox][ch] = (_Float16)fmaxf(best, 0.0f);
    }
    __syncthreads();

    // ---- conv2 MFMA: M=208 (52 pools x 4, 13 tiles), N=16/wave, K=32 ----
    int lane = tid & 63;
    int w = tid >> 6;
    int l16 = lane & 15;
    int quad = lane >> 4;
    int oc = w * 16 + l16;

    half8 bfrag[9];
#pragma unroll
    for (int t = 0; t < 9; ++t)
        bfrag[t] = *(const half8*)&w2h[(t * 64 + oc) * 32 + quad * 8];
    float bias = conv2_b[oc];
    u16* dstn = a2 + (size_t)n * 3136;

    for (int mt = 0; mt < 13; ++mt) {
        int m = mt * 16 + l16;           // pool-major row: m = pool*4 + sub
        int pool = m >> 2;
        int s = m & 3;
        int pc = pool < 49 ? pool : 48;  // clamp pad rows into bounds
        int y = 2 * (pc / 7) + (s >> 1); // un-padded pos 0..13
        int xq = 2 * (pc % 7) + (s & 1);
        floatx4 acc0 = {0.f, 0.f, 0.f, 0.f};
        floatx4 acc1 = {0.f, 0.f, 0.f, 0.f};
#pragma unroll
        for (int t = 0; t < 9; ++t) {
            int dy = t / 3, dx = t % 3;
            half8 av = *(const half8*)&a1s[y + dy][xq + dx][quad * 8];
            if (t & 1)
                acc1 = __builtin_amdgcn_mfma_f32_16x16x32_f16(av, bfrag[t],
                                                              acc1, 0, 0, 0);
            else
                acc0 = __builtin_amdgcn_mfma_f32_16x16x32_f16(av, bfrag[t],
                                                              acc0, 0, 0, 0);
        }
        // C/D: row(M)=quad*4+r, col(N)=l16 -> this lane owns pool mt*4+quad
        int pl = mt * 4 + quad;
        if (pl < 49) {
            float v0 = acc0[0] + acc1[0];
            float v1 = acc0[1] + acc1[1];
            float v2 = acc0[2] + acc1[2];
            float v3 = acc0[3] + acc1[3];
            float mx = fmaxf(fmaxf(v0, v1), fmaxf(v2, v3));
            dstn[pl * 64 + oc] = f2bf(fmaxf(mx + bias, 0.0f));
        }
    }
}

// ---------------------------------------------------------------------------
// fc1 (bf16 MFMA, M=16/block, N=32/wave, K=3136) + bias + relu -> LDS H tile
// + fc2 (16x10, K=128 fp32) in-block.  A = a2 pos-major, B = wbf (k-permuted).
// ---------------------------------------------------------------------------
__global__ __launch_bounds__(256) void fc_kernel(
        const u16* __restrict__ A, const u16* __restrict__ Wbf,
        const float* __restrict__ fc1_b, const float* __restrict__ fc2_w,
        const float* __restrict__ fc2_b, float* __restrict__ out) {
    __shared__ float Hs[16][132];
    int tid = threadIdx.x;
    int lane = tid & 63;
    int w = tid >> 6;
    int l16 = lane & 15;
    int quad = lane >> 4;
    int m0 = blockIdx.x * 16;

    const u16* aptr = A + (size_t)(m0 + l16) * 3136 + quad * 8;
    const u16* bptr0 = Wbf + (size_t)(w * 32 + l16) * 3136 + quad * 8;
    const u16* bptr1 = bptr0 + 16 * 3136;

    floatx4 acc0 = {0.f, 0.f, 0.f, 0.f};
    floatx4 acc1 = {0.f, 0.f, 0.f, 0.f};
#pragma unroll 4
    for (int k0 = 0; k0 < 3136; k0 += 32) {
        bs8 av = *(const bs8*)(aptr + k0);
        bs8 bv0 = *(const bs8*)(bptr0 + k0);
        bs8 bv1 = *(const bs8*)(bptr1 + k0);
        acc0 = __builtin_amdgcn_mfma_f32_16x16x32_bf16(av, bv0, acc0, 0, 0, 0);
        acc1 = __builtin_amdgcn_mfma_f32_16x16x32_bf16(av, bv1, acc1, 0, 0, 0);
    }
    // C/D: row(M)=quad*4+r, col(N)=l16
    int n0 = w * 32 + l16;
    float b0 = fc1_b[n0];
    float b1 = fc1_b[n0 + 16];
#pragma unroll
    for (int r = 0; r < 4; ++r) {
        int mr = quad * 4 + r;
        Hs[mr][n0] = fmaxf(acc0[r] + b0, 0.0f);
        Hs[mr][n0 + 16] = fmaxf(acc1[r] + b1, 0.0f);
    }
    __syncthreads();

    if (tid < 160) {
        int m = tid / 10, j = tid % 10;
        const float* wr = fc2_w + j * 128;
        float acc = fc2_b[j];
#pragma unroll 16
        for (int k = 0; k < 128; ++k) acc += Hs[m][k] * wr[k];
        out[(size_t)(m0 + m) * 10 + j] = acc;
    }
}

extern "C" void kernel_launch(void* const* d_in, const int* in_sizes, int n_in,
                              void* d_out, int out_size, void* d_ws,
                              size_t ws_size, hipStream_t stream) {
    const float* x       = (const float*)d_in[0];
    const float* theta   = (const float*)d_in[1];
    const float* sigma   = (const float*)d_in[2];
    const float* gamma   = (const float*)d_in[3];
    const float* lambd   = (const float*)d_in[4];
    const float* psi     = (const float*)d_in[5];
    const float* conv2_w = (const float*)d_in[6];
    const float* conv2_b = (const float*)d_in[7];
    const float* fc1_w   = (const float*)d_in[8];
    const float* fc1_b   = (const float*)d_in[9];
    const float* fc2_w   = (const float*)d_in[10];
    const float* fc2_b   = (const float*)d_in[11];
    float* out = (float*)d_out;

    // ws layout (26.5 MB):
    //   a2  bf16 pos-major  : 0          .. 25,690,112
    //   w1g fp32 [288]      : 25,690,112 (+4096)
    //   w2h f16 [9][64][32] : 25,694,208 (+36,864)
    //   wbf bf16 [128][3136]: 25,731,072 (+802,816)
    char* ws = (char*)d_ws;
    u16* a2 = (u16*)ws;
    float* w1g = (float*)(ws + 25690112ull);
    _Float16* w2h = (_Float16*)(ws + 25694208ull);
    u16* wbf = (u16*)(ws + 25731072ull);

    prep_kernel<<<1642, 256, 0, stream>>>(theta, sigma, gamma, lambd, psi,
                                          conv2_w, fc1_w, w1g, w2h, wbf);
    fused_conv_kernel<<<BATCH, 256, 0, stream>>>(x, w1g, w2h, conv2_b, a2);
    fc_kernel<<<BATCH / 16, 256, 0, stream>>>(a2, wbf, fc1_b, fc2_w, fc2_b,
                                              out);
}

// Round 8
// 185.346 us; speedup vs baseline: 6.6424x; 1.3478x over previous
//
#include <hip/hip_runtime.h>
#include <hip/hip_bf16.h>

#define BATCH 4096

typedef unsigned short u16;
typedef _Float16 half4 __attribute__((ext_vector_type(4)));
typedef _Float16 half8 __attribute__((ext_vector_type(8)));
typedef short bs8 __attribute__((ext_vector_type(8)));
typedef float floatx4 __attribute__((ext_vector_type(4)));

__device__ inline u16 f2bf(float f) {
    union { float f; unsigned int i; } u;
    u.f = f;
    unsigned int lsb = (u.i >> 16) & 1u;
    unsigned int r = u.i + 0x7fffu + lsb;   // RNE
    if ((u.i & 0x7f800000u) == 0x7f800000u) r = u.i;
    return (u16)(r >> 16);
}

// ---------------------------------------------------------------------------
// Prep (once per call; everything stays L2-resident):
//  w1h : gabor+identity bank, f16 [32 ch][16 taps] zero-padded K 9->16
//  w2h : conv2_w f16 [tap][oc][ic]
//  wbf : fc1_w bf16 [n][k'], k' = pool*64+oc (matches pos-major a2)
// ---------------------------------------------------------------------------
__global__ __launch_bounds__(256) void prep_kernel(
        const float* __restrict__ theta, const float* __restrict__ sigma,
        const float* __restrict__ gamma, const float* __restrict__ lambd,
        const float* __restrict__ psi, const float* __restrict__ conv2_w,
        const float* __restrict__ fc1_w, _Float16* __restrict__ w1h,
        _Float16* __restrict__ w2h, u16* __restrict__ wbf) {
    int id = blockIdx.x * 256 + threadIdx.x;
    if (id < 512) {
        int g = id >> 4, t = id & 15;
        float v = 0.0f;
        if (t < 9) {
            int i = t / 3, j = t % 3;
            float xg = (float)i - 1.0f;      // meshgrid 'ij'
            float yg = (float)j - 1.0f;
            if (g < 16) {
                float th = theta[g];
                float c = cosf(th), s = sinf(th);
                float xt = xg * c + yg * s;
                float yt = -xg * s + yg * c;
                float sx = sigma[g];
                float sy = sx / gamma[g];
                float env = expf(-0.5f *
                                 (xt * xt / (sx * sx) + yt * yt / (sy * sy)));
                float car =
                    cosf(6.28318530717958647692f * xt / lambd[g] + psi[g]);
                v = env * car;
            } else {
                v = (t == 4) ? 1.0f : 0.0f;   // identity: i==1 && j==1
            }
        }
        w1h[id] = (_Float16)v;
    } else if (id < 512 + 18432) {
        int t2 = id - 512;
        int tap = t2 / 2048, rem = t2 % 2048;
        int oc = rem / 32, ic = rem % 32;
        w2h[t2] = (_Float16)conv2_w[(oc * 32 + ic) * 9 + tap];
    } else {
        int t3 = id - 512 - 18432;            // < 401408 (grid sized exactly)
        int nrow = t3 / 3136, kp = t3 % 3136;
        int pool = kp / 64, oc = kp % 64;
        wbf[t3] = f2bf(fc1_w[(size_t)nrow * 3136 + oc * 49 + pool]);
    }
}

// ---------------------------------------------------------------------------
// Fused conv, both convs on MFMA:
//  conv1: M=784 pre-pool positions pool-major, N=32 ch, K=16 (9 taps padded),
//         A-frag gathered per-lane from img LDS, pool+relu in C-regs -> a1s.
//  conv2: 9 tap-wise GEMMs K=32, M pool-major, pool+bias+relu in C-regs
//         -> a2 pos-major (4096)[49][64] bf16.
// ---------------------------------------------------------------------------
__global__ __launch_bounds__(256) void fused_conv_kernel(
        const float* __restrict__ x, const _Float16* __restrict__ w1h,
        const _Float16* __restrict__ w2h, const float* __restrict__ conv2_b,
        u16* __restrict__ a2) {
    __shared__ float img[30][31];
    __shared__ __align__(16) _Float16 a1s[16][16][40];  // ch-last, stride 40

    int n = blockIdx.x;
    int tid = threadIdx.x;

    for (int i = tid; i < 30 * 31; i += 256) (&img[0][0])[i] = 0.0f;
    for (int i = tid; i < 1280; i += 256)       // 16*16*40*2B = 1280 int4
        ((int4*)&a1s[0][0][0])[i] = int4{0, 0, 0, 0};
    __syncthreads();

    const float* xim = x + (size_t)n * 784;
    for (int i = tid; i < 784; i += 256)
        img[i / 28 + 1][i % 28 + 1] = xim[i];
    __syncthreads();

    int lane = tid & 63;
    int w = tid >> 6;
    int l16 = lane & 15;
    int quad = lane >> 4;

    // ---- conv1 MFMA ----
    half4 b1a = *(const half4*)&w1h[l16 * 16 + quad * 4];
    half4 b1b = *(const half4*)&w1h[(16 + l16) * 16 + quad * 4];
    int t0 = quad * 4;
    int dy0 = t0 / 3, dx0 = t0 % 3;           // per-lane tap meta (quad-const)
    int dy1 = (t0 + 1) / 3, dx1 = (t0 + 1) % 3;
    int dy2 = (t0 + 2) / 3, dx2 = (t0 + 2) % 3;
    int dy3 = (t0 + 3) / 3, dx3 = (t0 + 3) % 3;

    for (int mt = w; mt < 49; mt += 4) {
        int m = mt * 16 + l16;                 // pool-major: pool=m>>2, sub=m&3
        int pool = m >> 2, sub = m & 3;
        int y = 2 * (pool / 14) + (sub >> 1);
        int xx = 2 * (pool % 14) + (sub & 1);
        half4 av;
        av[0] = (_Float16)(t0 < 9 ? img[y + dy0][xx + dx0] : 0.0f);
        av[1] = (_Float16)(t0 + 1 < 9 ? img[y + dy1][xx + dx1] : 0.0f);
        av[2] = (_Float16)(t0 + 2 < 9 ? img[y + dy2][xx + dx2] : 0.0f);
        av[3] = (_Float16)(t0 + 3 < 9 ? img[y + dy3][xx + dx3] : 0.0f);
        floatx4 c0 = {0.f, 0.f, 0.f, 0.f};
        floatx4 c1 = {0.f, 0.f, 0.f, 0.f};
        c0 = __builtin_amdgcn_mfma_f32_16x16x16f16(av, b1a, c0, 0, 0, 0);
        c1 = __builtin_amdgcn_mfma_f32_16x16x16f16(av, b1b, c1, 0, 0, 0);
        // lane owns pool mt*4+quad; C rows r = sub 0..3 of that pool
        int pl = mt * 4 + quad;
        int py = pl / 14, px = pl % 14;
        float v0 = fmaxf(fmaxf(c0[0], c0[1]), fmaxf(c0[2], c0[3]));
        float v1 = fmaxf(fmaxf(c1[0], c1[1]), fmaxf(c1[2], c1[3]));
        a1s[1 + py][1 + px][l16] = (_Float16)fmaxf(v0, 0.0f);
        a1s[1 + py][1 + px][16 + l16] = (_Float16)fmaxf(v1, 0.0f);
    }
    __syncthreads();

    // ---- conv2 MFMA: M=208 pool-major (13 tiles), N=16/wave, K=32 ----
    int oc = w * 16 + l16;
    half8 bfrag[9];
#pragma unroll
    for (int t = 0; t < 9; ++t)
        bfrag[t] = *(const half8*)&w2h[(t * 64 + oc) * 32 + quad * 8];
    float bias = conv2_b[oc];
    u16* dstn = a2 + (size_t)n * 3136;

    for (int mt = 0; mt < 13; ++mt) {
        int m = mt * 16 + l16;
        int pool = m >> 2;
        int s = m & 3;
        int pc = pool < 49 ? pool : 48;        // clamp pad rows
        int y = 2 * (pc / 7) + (s >> 1);
        int xq = 2 * (pc % 7) + (s & 1);
        floatx4 acc0 = {0.f, 0.f, 0.f, 0.f};
        floatx4 acc1 = {0.f, 0.f, 0.f, 0.f};
#pragma unroll
        for (int t = 0; t < 9; ++t) {
            int dy = t / 3, dx = t % 3;
            half8 av = *(const half8*)&a1s[y + dy][xq + dx][quad * 8];
            if (t & 1)
                acc1 = __builtin_amdgcn_mfma_f32_16x16x32_f16(av, bfrag[t],
                                                              acc1, 0, 0, 0);
            else
                acc0 = __builtin_amdgcn_mfma_f32_16x16x32_f16(av, bfrag[t],
                                                              acc0, 0, 0, 0);
        }
        int pl = mt * 4 + quad;
        if (pl < 49) {
            float v0 = acc0[0] + acc1[0];
            float v1 = acc0[1] + acc1[1];
            float v2 = acc0[2] + acc1[2];
            float v3 = acc0[3] + acc1[3];
            float mx = fmaxf(fmaxf(v0, v1), fmaxf(v2, v3));
            dstn[pl * 64 + oc] = f2bf(fmaxf(mx + bias, 0.0f));
        }
    }
}

// ---------------------------------------------------------------------------
// fc1 + fc2, one block of 512 threads per 16 images.
// 8 waves = 2 K-halves (1568 = 49x32) x 4 N-tiles of 32. Partials -> LDS,
// then bias+relu+fc2 dot in-block. 2 blocks/CU -> 4 waves/SIMD.
// ---------------------------------------------------------------------------
__global__ __launch_bounds__(512) void fc_kernel(
        const u16* __restrict__ A, const u16* __restrict__ Wbf,
        const float* __restrict__ fc1_b, const float* __restrict__ fc2_w,
        const float* __restrict__ fc2_b, float* __restrict__ out) {
    __shared__ float Hs[2][16][132];
    int tid = threadIdx.x;
    int lane = tid & 63;
    int w = tid >> 6;                  // 0..7
    int l16 = lane & 15;
    int quad = lane >> 4;
    int kc = w >> 2;                   // K-half
    int wsub = w & 3;                  // N-tile group
    int m0 = blockIdx.x * 16;

    size_t ko = (size_t)kc * 1568 + quad * 8;
    const u16* aptr = A + (size_t)(m0 + l16) * 3136 + ko;
    const u16* bptr0 = Wbf + (size_t)(wsub * 32 + l16) * 3136 + ko;
    const u16* bptr1 = bptr0 + 16 * 3136;

    floatx4 acc0 = {0.f, 0.f, 0.f, 0.f};
    floatx4 acc1 = {0.f, 0.f, 0.f, 0.f};
#pragma unroll 7
    for (int k0 = 0; k0 < 1568; k0 += 32) {
        bs8 av = *(const bs8*)(aptr + k0);
        bs8 bv0 = *(const bs8*)(bptr0 + k0);
        bs8 bv1 = *(const bs8*)(bptr1 + k0);
        acc0 = __builtin_amdgcn_mfma_f32_16x16x32_bf16(av, bv0, acc0, 0, 0, 0);
        acc1 = __builtin_amdgcn_mfma_f32_16x16x32_bf16(av, bv1, acc1, 0, 0, 0);
    }
    int n0 = wsub * 32 + l16;
#pragma unroll
    for (int r = 0; r < 4; ++r) {
        int mr = quad * 4 + r;
        Hs[kc][mr][n0] = acc0[r];
        Hs[kc][mr][n0 + 16] = acc1[r];
    }
    __syncthreads();

    if (tid < 160) {
        int m = tid / 10, j = tid % 10;
        const float* wr = fc2_w + j * 128;
        float acc = fc2_b[j];
#pragma unroll 16
        for (int k = 0; k < 128; ++k) {
            float h = fmaxf(Hs[0][m][k] + Hs[1][m][k] + fc1_b[k], 0.0f);
            acc += h * wr[k];
        }
        out[(size_t)(m0 + m) * 10 + j] = acc;
    }
}

extern "C" void kernel_launch(void* const* d_in, const int* in_sizes, int n_in,
                              void* d_out, int out_size, void* d_ws,
                              size_t ws_size, hipStream_t stream) {
    const float* x       = (const float*)d_in[0];
    const float* theta   = (const float*)d_in[1];
    const float* sigma   = (const float*)d_in[2];
    const float* gamma   = (const float*)d_in[3];
    const float* lambd   = (const float*)d_in[4];
    const float* psi     = (const float*)d_in[5];
    const float* conv2_w = (const float*)d_in[6];
    const float* conv2_b = (const float*)d_in[7];
    const float* fc1_w   = (const float*)d_in[8];
    const float* fc1_b   = (const float*)d_in[9];
    const float* fc2_w   = (const float*)d_in[10];
    const float* fc2_b   = (const float*)d_in[11];
    float* out = (float*)d_out;

    // ws (26.53 MB total):
    //   a2  bf16 pos-major [4096][49*64] : 0          (25,690,112 B)
    //   w1h f16 [32][16]                 : 25,690,112 (1,024 B)
    //   w2h f16 [9][64][32]              : 25,691,136 (36,864 B)
    //   wbf bf16 [128][3136]             : 25,728,000 (802,816 B)
    char* ws = (char*)d_ws;
    u16* a2 = (u16*)ws;
    _Float16* w1h = (_Float16*)(ws + 25690112ull);
    _Float16* w2h = (_Float16*)(ws + 25691136ull);
    u16* wbf = (u16*)(ws + 25728000ull);

    prep_kernel<<<1642, 256, 0, stream>>>(theta, sigma, gamma, lambd, psi,
                                          conv2_w, fc1_w, w1h, w2h, wbf);
    fused_conv_kernel<<<BATCH, 256, 0, stream>>>(x, w1h, w2h, conv2_b, a2);
    fc_kernel<<<BATCH / 16, 512, 0, stream>>>(a2, wbf, fc1_b, fc2_w, fc2_b,
                                              out);
}